// Round 1
// baseline (252.968 us; speedup 1.0000x reference)
//
#include <hip/hip_runtime.h>

// ROI point pooling: for each anchor (box), take the first n points (in point
// order) inside the box, output anchor-local (x-cx, y-cy, z) padded to [A,n,3],
// plus counts[A] = min(#inside, n) written as float values.
//
// One block of 256 threads per anchor. Points scanned in 256-chunks with an
// ordered compaction: 64-lane ballot + popc lane prefix within each wave,
// 4 wave totals combined through LDS. Deterministic first-n in point order.

__global__ __launch_bounds__(256) void roi_pool_kernel(
    const float* __restrict__ pts,   // [N,3]
    const float* __restrict__ anc,   // [A,6] cx,cy,cz,w,l,h
    float* __restrict__ out_pts,     // [A,n,3]
    float* __restrict__ out_cnt,     // [A]   (float-valued counts)
    int N, int n)
{
    const int a = blockIdx.x;
    const float cx = anc[a * 6 + 0];
    const float cy = anc[a * 6 + 1];
    const float w  = anc[a * 6 + 3];
    const float l  = anc[a * 6 + 4];
    const float h  = anc[a * 6 + 5];
    const float xmin = cx - 0.5f * w, xmax = cx + 0.5f * w;
    const float ymin = cy - 0.5f * l, ymax = cy + 0.5f * l;

    const int tid  = threadIdx.x;
    const int wave = tid >> 6;
    const int lane = tid & 63;

    __shared__ int s_tot[4];

    int base = 0;  // running in-box count, identical across all threads
    float* const outa = out_pts + (size_t)a * n * 3;

    for (int start = 0; start < N; start += 256) {
        const int i = start + tid;
        bool m = false;
        float px = 0.f, py = 0.f, pz = 0.f;
        if (i < N) {
            px = pts[3 * i + 0];
            py = pts[3 * i + 1];
            pz = pts[3 * i + 2];
            m = (px >= xmin) & (px <= xmax) &
                (py >= ymin) & (py <= ymax) &
                (pz >= 0.0f) & (pz <= h);
        }
        const unsigned long long ball = __ballot(m);
        const int lanePfx = __popcll(ball & ((1ull << lane) - 1ull));
        if (lane == 0) s_tot[wave] = __popcll(ball);
        __syncthreads();
        const int t0 = s_tot[0], t1 = s_tot[1], t2 = s_tot[2], t3 = s_tot[3];
        int offs = base;
        if (wave > 0) offs += t0;
        if (wave > 1) offs += t1;
        if (wave > 2) offs += t2;
        const int slot = offs + lanePfx;
        if (m && slot < n) {
            float* o = outa + (size_t)slot * 3;
            o[0] = px - cx;
            o[1] = py - cy;
            o[2] = pz;
        }
        base += t0 + t1 + t2 + t3;
        __syncthreads();  // protect s_tot before next chunk overwrites it
        if (base >= n) break;  // counts clamp at n; later points irrelevant
    }

    const int count = base < n ? base : n;
    if (tid == 0) out_cnt[a] = (float)count;

    // Zero the padded tail (d_out is 0xAA-poisoned before every timed launch).
    for (int s = count + tid; s < n; s += 256) {
        float* o = outa + (size_t)s * 3;
        o[0] = 0.f; o[1] = 0.f; o[2] = 0.f;
    }
}

extern "C" void kernel_launch(void* const* d_in, const int* in_sizes, int n_in,
                              void* d_out, int out_size, void* d_ws, size_t ws_size,
                              hipStream_t stream) {
    const float* pts = (const float*)d_in[0];
    const float* anc = (const float*)d_in[1];
    const int N = in_sizes[0] / 3;          // 100000
    const int A = in_sizes[1] / 6;          // 1024
    const int n = (out_size / A - 1) / 3;   // 512 (derived: out = A*n*3 + A)

    float* out_pts = (float*)d_out;
    float* out_cnt = (float*)d_out + (size_t)A * n * 3;

    roi_pool_kernel<<<dim3(A), dim3(256), 0, stream>>>(pts, anc, out_pts, out_cnt, N, n);
}

// Round 2
// 233.393 us; speedup vs baseline: 1.0839x; 1.0839x over previous
//
#include <hip/hip_runtime.h>

// ROI point pooling, barrier-free 3-phase version.
//
// Phase 1 (mask_kernel): one wave per (anchor, segment). Each wave tests 64
//   consecutive points per iteration against its anchor box; __ballot(m) IS
//   the 64-bit occupancy word -> store to ws mask, accumulate popcount into
//   per-(anchor,segment) counts. No LDS, no barriers, 128 waves/CU.
// Phase 2 (zero_kernel): clear d_out (harness poisons it with 0xAA).
// Phase 3 (emit_kernel): one wave per (anchor, segment). Shfl-scan the 32
//   segment counts -> deterministic base slot; walk mask words, gather the
//   in-box points, write anchor-local coords to ordered slots < n. Lane 0 of
//   segment 0 writes counts[a] = min(total, n).
//
// Slot of point i = #(in-box points with index < i)  == reference cumsum.

#define SEGS 32

__global__ __launch_bounds__(256) void mask_kernel(
    const float* __restrict__ pts, const float* __restrict__ anc,
    unsigned long long* __restrict__ mask, int* __restrict__ cnt,
    int N, int run, int W, int AS)
{
    const int wid  = blockIdx.x * 4 + (threadIdx.x >> 6);
    const int lane = threadIdx.x & 63;
    if (wid >= AS) return;
    const int a = wid / SEGS, s = wid % SEGS;

    const float cx = anc[a * 6 + 0], cy = anc[a * 6 + 1];
    const float w  = anc[a * 6 + 3], l  = anc[a * 6 + 4], h = anc[a * 6 + 5];
    const float xmin = cx - 0.5f * w, xmax = cx + 0.5f * w;
    const float ymin = cy - 0.5f * l, ymax = cy + 0.5f * l;

    const int w0 = s * run;
    const int w1 = min(w0 + run, W);
    unsigned long long* mrow = mask + (size_t)a * (SEGS * run);

    int c = 0;
    for (int wd = w0; wd < w1; ++wd) {
        const int i = wd * 64 + lane;
        bool m = false;
        if (i < N) {
            const float px = pts[3 * i + 0];
            const float py = pts[3 * i + 1];
            const float pz = pts[3 * i + 2];
            m = (px >= xmin) & (px <= xmax) &
                (py >= ymin) & (py <= ymax) &
                (pz >= 0.0f) & (pz <= h);
        }
        const unsigned long long b = __ballot(m);
        if (lane == 0) {
            mrow[wd] = b;
            c += __popcll(b);
        }
    }
    if (lane == 0) cnt[a * SEGS + s] = c;
}

__global__ __launch_bounds__(256) void zero_kernel(float* __restrict__ p, int n)
{
    const int i4 = blockIdx.x * blockDim.x + threadIdx.x;
    if (4 * i4 + 3 < n) {
        ((float4*)p)[i4] = make_float4(0.f, 0.f, 0.f, 0.f);
    } else {
        for (int j = 4 * i4; j < n; ++j) p[j] = 0.f;  // tail (rarely taken)
    }
}

__global__ __launch_bounds__(256) void emit_kernel(
    const float* __restrict__ pts, const float* __restrict__ anc,
    const unsigned long long* __restrict__ mask, const int* __restrict__ cnt,
    float* __restrict__ out_pts, float* __restrict__ out_cnt,
    int N, int n, int run, int W, int AS)
{
    const int wid  = blockIdx.x * 4 + (threadIdx.x >> 6);
    const int lane = threadIdx.x & 63;
    if (wid >= AS) return;
    const int a = wid / SEGS, s = wid % SEGS;

    // Scan the 32 segment counts across lanes for deterministic bases.
    const int v = (lane < SEGS) ? cnt[a * SEGS + lane] : 0;
    int incl = v;
    #pragma unroll
    for (int d = 1; d < 64; d <<= 1) {
        const int t = __shfl_up(incl, d);
        if (lane >= d) incl += t;
    }
    const int total = __shfl(incl, SEGS - 1);
    int base = __shfl(incl, s) - __shfl(v, s);  // exclusive prefix of segment s

    if (s == 0 && lane == 0) out_cnt[a] = (float)min(total, n);
    if (base >= n) return;  // this segment's points all fall past the clamp

    const float cx = anc[a * 6 + 0], cy = anc[a * 6 + 1];
    const unsigned long long* mrow = mask + (size_t)a * (SEGS * run);
    float* const outa = out_pts + (size_t)a * n * 3;

    const int w0 = s * run;
    const int w1 = min(w0 + run, W);
    for (int wd = w0; wd < w1 && base < n; ++wd) {
        const unsigned long long b = mrow[wd];
        const bool m = (b >> lane) & 1ull;
        const int slot = base + __popcll(b & ((1ull << lane) - 1ull));
        if (m && slot < n) {
            const int i = wd * 64 + lane;
            float* o = outa + (size_t)slot * 3;
            o[0] = pts[3 * i + 0] - cx;
            o[1] = pts[3 * i + 1] - cy;
            o[2] = pts[3 * i + 2];
        }
        base += __popcll(b);
    }
}

// ---- Fallback (round-1 kernel) used only if ws_size is too small ----
__global__ __launch_bounds__(256) void roi_pool_kernel(
    const float* __restrict__ pts, const float* __restrict__ anc,
    float* __restrict__ out_pts, float* __restrict__ out_cnt, int N, int n)
{
    const int a = blockIdx.x;
    const float cx = anc[a * 6 + 0], cy = anc[a * 6 + 1];
    const float w  = anc[a * 6 + 3], l  = anc[a * 6 + 4], h = anc[a * 6 + 5];
    const float xmin = cx - 0.5f * w, xmax = cx + 0.5f * w;
    const float ymin = cy - 0.5f * l, ymax = cy + 0.5f * l;
    const int tid = threadIdx.x, wave = tid >> 6, lane = tid & 63;
    __shared__ int s_tot[4];
    int base = 0;
    float* const outa = out_pts + (size_t)a * n * 3;
    for (int start = 0; start < N; start += 256) {
        const int i = start + tid;
        bool m = false;
        float px = 0.f, py = 0.f, pz = 0.f;
        if (i < N) {
            px = pts[3 * i]; py = pts[3 * i + 1]; pz = pts[3 * i + 2];
            m = (px >= xmin) & (px <= xmax) & (py >= ymin) & (py <= ymax) &
                (pz >= 0.0f) & (pz <= h);
        }
        const unsigned long long ball = __ballot(m);
        const int lanePfx = __popcll(ball & ((1ull << lane) - 1ull));
        if (lane == 0) s_tot[wave] = __popcll(ball);
        __syncthreads();
        const int t0 = s_tot[0], t1 = s_tot[1], t2 = s_tot[2], t3 = s_tot[3];
        int offs = base;
        if (wave > 0) offs += t0;
        if (wave > 1) offs += t1;
        if (wave > 2) offs += t2;
        const int slot = offs + lanePfx;
        if (m && slot < n) {
            float* o = outa + (size_t)slot * 3;
            o[0] = px - cx; o[1] = py - cy; o[2] = pz;
        }
        base += t0 + t1 + t2 + t3;
        __syncthreads();
        if (base >= n) break;
    }
    const int count = base < n ? base : n;
    if (tid == 0) out_cnt[a] = (float)count;
    for (int s = count + tid; s < n; s += 256) {
        float* o = outa + (size_t)s * 3;
        o[0] = 0.f; o[1] = 0.f; o[2] = 0.f;
    }
}

extern "C" void kernel_launch(void* const* d_in, const int* in_sizes, int n_in,
                              void* d_out, int out_size, void* d_ws, size_t ws_size,
                              hipStream_t stream) {
    const float* pts = (const float*)d_in[0];
    const float* anc = (const float*)d_in[1];
    const int N = in_sizes[0] / 3;          // 100000
    const int A = in_sizes[1] / 6;          // 1024
    const int n = (out_size / A - 1) / 3;   // 512

    float* out_pts = (float*)d_out;
    float* out_cnt = (float*)d_out + (size_t)A * n * 3;

    const int W   = (N + 63) / 64;          // mask words per anchor (1563)
    const int run = (W + SEGS - 1) / SEGS;  // words per segment (49)
    const size_t mask_bytes = (size_t)A * SEGS * run * sizeof(unsigned long long);
    const size_t cnt_bytes  = (size_t)A * SEGS * sizeof(int);

    if (ws_size < mask_bytes + cnt_bytes) {
        // Workspace too small: barrier-based single-kernel fallback.
        roi_pool_kernel<<<dim3(A), dim3(256), 0, stream>>>(pts, anc, out_pts, out_cnt, N, n);
        return;
    }

    unsigned long long* mask = (unsigned long long*)d_ws;
    int* cnt = (int*)((char*)d_ws + mask_bytes);

    const int AS = A * SEGS;                       // 32768 waves
    const int blocks = (AS + 3) / 4;               // 4 waves per block

    mask_kernel<<<dim3(blocks), dim3(256), 0, stream>>>(pts, anc, mask, cnt, N, run, W, AS);
    zero_kernel<<<dim3((out_size / 4 + 255) / 256), dim3(256), 0, stream>>>((float*)d_out, out_size);
    emit_kernel<<<dim3(blocks), dim3(256), 0, stream>>>(pts, anc, mask, cnt,
                                                        out_pts, out_cnt, N, n, run, W, AS);
}

// Round 3
// 202.475 us; speedup vs baseline: 1.2494x; 1.1527x over previous
//
#include <hip/hip_runtime.h>

// ROI point pooling, transposed 3-phase version.
//
// Phase 1 (mask_kernel): lane = anchor. A wave owns 64 anchors x an 8-word
//   (512-point) segment. Point coords are wave-uniform -> scalar loads shared
//   by all 64 anchors; test = 6 v_cmp + SALU mask combine + 2-VALU bit
//   deposit. Produces bit matrix mask[word][anchor] (coalesced u64 stores).
// Phase 2 (scan_kernel): wave = anchor. Popcount+scan mask words ->
//   per-super-block (64-word) exclusive bases; writes counts[a] and zeroes
//   the padded output tail (d_out is 0xAA-poisoned every call).
// Phase 3 (emit_kernel): wave = (anchor, super-block). One 64-lane gather of
//   the super-block's words, register scan, then ffs-loop over non-empty
//   words only; gathers in-box points and writes ordered slots < n.
//
// Slot of point i = #(in-box points with index < i)  == reference cumsum.

#define WPS 8                    // words per mask segment (512 points)

__global__ __launch_bounds__(256) void mask_kernel(
    const float* __restrict__ pts, const float* __restrict__ anc,
    unsigned long long* __restrict__ mask,
    int N, int W, int A, int SEGS, int NGRP)
{
    const int wv   = blockIdx.x * 4 + (threadIdx.x >> 6);
    const int lane = threadIdx.x & 63;
    if (wv >= NGRP * SEGS) return;
    const int s = wv / NGRP;          // segment (consecutive waves share points)
    const int g = wv % NGRP;          // anchor group
    const int a = g * 64 + lane;

    float xl, xh, yl, yh, h;
    {
        const float cx = anc[a * 6 + 0], cy = anc[a * 6 + 1];
        const float w  = anc[a * 6 + 3], l  = anc[a * 6 + 4];
        h = anc[a * 6 + 5];
        xl = cx - 0.5f * w; xh = cx + 0.5f * w;
        yl = cy - 0.5f * l; yh = cy + 0.5f * l;
    }

    const int w0 = s * WPS;
    const int w1 = min(w0 + WPS, W);
    for (int wd = w0; wd < w1; ++wd) {
        const int pbase = wd * 64;
        unsigned long long word = 0ull;
        if (pbase + 64 <= N) {
            #pragma unroll 16
            for (int p = 0; p < 64; ++p) {
                const float px = pts[(pbase + p) * 3 + 0];  // wave-uniform -> s_load
                const float py = pts[(pbase + p) * 3 + 1];
                const float pz = pts[(pbase + p) * 3 + 2];
                const bool m = (px >= xl) & (px <= xh) &
                               (py >= yl) & (py <= yh) &
                               (pz >= 0.0f) & (pz <= h);
                if (m) word |= (1ull << p);
            }
        } else {
            const int pcnt = N - pbase;
            for (int p = 0; p < pcnt; ++p) {
                const float px = pts[(pbase + p) * 3 + 0];
                const float py = pts[(pbase + p) * 3 + 1];
                const float pz = pts[(pbase + p) * 3 + 2];
                const bool m = (px >= xl) & (px <= xh) &
                               (py >= yl) & (py <= yh) &
                               (pz >= 0.0f) & (pz <= h);
                if (m) word |= (1ull << p);
            }
        }
        mask[(size_t)wd * A + a] = word;   // coalesced 512B store
    }
}

// bases[sb*A + a] = #in-box points of anchor a before word sb*64 (exclusive).
// bases[NSB*A + a] = total. Also writes counts and zeroes the output tail.
__global__ __launch_bounds__(256) void scan_kernel(
    const unsigned long long* __restrict__ mask, int* __restrict__ bases,
    float* __restrict__ out_pts, float* __restrict__ out_cnt,
    int W, int A, int NSB, int n)
{
    const int a    = blockIdx.x * 4 + (threadIdx.x >> 6);
    const int lane = threadIdx.x & 63;
    if (a >= A) return;

    int run = 0;
    for (int sb = 0; sb < NSB; ++sb) {
        const int wd = sb * 64 + lane;
        const unsigned long long wm =
            (wd < W) ? mask[(size_t)wd * A + a] : 0ull;
        int pc = __popcll(wm);
        if (lane == 0) bases[sb * A + a] = run;
        #pragma unroll
        for (int d = 1; d < 64; d <<= 1) pc += __shfl_xor(pc, d);
        run += pc;  // pc now wave-uniform total
    }
    if (lane == 0) bases[NSB * A + a] = run;

    const int count = run < n ? run : n;
    if (lane == 0) out_cnt[a] = (float)count;

    float* const outa = out_pts + (size_t)a * n * 3;
    for (int f = count * 3 + lane; f < n * 3; f += 64) outa[f] = 0.0f;
}

__global__ __launch_bounds__(256) void emit_kernel(
    const float* __restrict__ pts, const float* __restrict__ anc,
    const unsigned long long* __restrict__ mask, const int* __restrict__ bases,
    float* __restrict__ out_pts, int N, int n, int W, int A, int NSB)
{
    const int wv   = blockIdx.x * 4 + (threadIdx.x >> 6);
    const int lane = threadIdx.x & 63;
    if (wv >= A * NSB) return;
    const int sb = wv / A;            // consecutive waves share mask cachelines
    const int a  = wv % A;

    const int base0 = bases[sb * A + a];
    if (base0 >= n) return;           // everything here lands past the clamp

    const int wd = sb * 64 + lane;
    const unsigned long long wm = (wd < W) ? mask[(size_t)wd * A + a] : 0ull;
    int pc = __popcll(wm);
    int incl = pc;
    #pragma unroll
    for (int d = 1; d < 64; d <<= 1) {
        const int t = __shfl_up(incl, d);
        if (lane >= d) incl += t;
    }
    const int wbase = base0 + (incl - pc);

    unsigned long long occ = __ballot(wm != 0ull && wbase < n);

    const float cx = anc[a * 6 + 0], cy = anc[a * 6 + 1];
    float* const outa = out_pts + (size_t)a * n * 3;

    while (occ) {
        const int w = __ffsll((long long)occ) - 1;
        occ &= occ - 1ull;
        const unsigned long long b = __shfl(wm, w);
        const int wb = __shfl(wbase, w);
        const bool m = (b >> lane) & 1ull;
        const int slot = wb + __popcll(b & ((1ull << lane) - 1ull));
        if (m && slot < n) {
            const int i = (sb * 64 + w) * 64 + lane;
            float* o = outa + (size_t)slot * 3;
            o[0] = pts[3 * i + 0] - cx;
            o[1] = pts[3 * i + 1] - cy;
            o[2] = pts[3 * i + 2];
        }
    }
}

// ---- Fallback (round-1 kernel) used only if ws_size is too small ----
__global__ __launch_bounds__(256) void roi_pool_kernel(
    const float* __restrict__ pts, const float* __restrict__ anc,
    float* __restrict__ out_pts, float* __restrict__ out_cnt, int N, int n)
{
    const int a = blockIdx.x;
    const float cx = anc[a * 6 + 0], cy = anc[a * 6 + 1];
    const float w  = anc[a * 6 + 3], l  = anc[a * 6 + 4], h = anc[a * 6 + 5];
    const float xmin = cx - 0.5f * w, xmax = cx + 0.5f * w;
    const float ymin = cy - 0.5f * l, ymax = cy + 0.5f * l;
    const int tid = threadIdx.x, wave = tid >> 6, lane = tid & 63;
    __shared__ int s_tot[4];
    int base = 0;
    float* const outa = out_pts + (size_t)a * n * 3;
    for (int start = 0; start < N; start += 256) {
        const int i = start + tid;
        bool m = false;
        float px = 0.f, py = 0.f, pz = 0.f;
        if (i < N) {
            px = pts[3 * i]; py = pts[3 * i + 1]; pz = pts[3 * i + 2];
            m = (px >= xmin) & (px <= xmax) & (py >= ymin) & (py <= ymax) &
                (pz >= 0.0f) & (pz <= h);
        }
        const unsigned long long ball = __ballot(m);
        const int lanePfx = __popcll(ball & ((1ull << lane) - 1ull));
        if (lane == 0) s_tot[wave] = __popcll(ball);
        __syncthreads();
        const int t0 = s_tot[0], t1 = s_tot[1], t2 = s_tot[2], t3 = s_tot[3];
        int offs = base;
        if (wave > 0) offs += t0;
        if (wave > 1) offs += t1;
        if (wave > 2) offs += t2;
        const int slot = offs + lanePfx;
        if (m && slot < n) {
            float* o = outa + (size_t)slot * 3;
            o[0] = px - cx; o[1] = py - cy; o[2] = pz;
        }
        base += t0 + t1 + t2 + t3;
        __syncthreads();
        if (base >= n) break;
    }
    const int count = base < n ? base : n;
    if (tid == 0) out_cnt[a] = (float)count;
    for (int s = count + tid; s < n; s += 256) {
        float* o = outa + (size_t)s * 3;
        o[0] = 0.f; o[1] = 0.f; o[2] = 0.f;
    }
}

extern "C" void kernel_launch(void* const* d_in, const int* in_sizes, int n_in,
                              void* d_out, int out_size, void* d_ws, size_t ws_size,
                              hipStream_t stream) {
    const float* pts = (const float*)d_in[0];
    const float* anc = (const float*)d_in[1];
    const int N = in_sizes[0] / 3;          // 100000
    const int A = in_sizes[1] / 6;          // 1024
    const int n = (out_size / A - 1) / 3;   // 512

    float* out_pts = (float*)d_out;
    float* out_cnt = (float*)d_out + (size_t)A * n * 3;

    const int W    = (N + 63) / 64;         // mask words per anchor (1563)
    const int SEGS = (W + WPS - 1) / WPS;   // mask segments (196)
    const int NSB  = (W + 63) / 64;         // 64-word super-blocks (25)
    const int NGRP = (A + 63) / 64;         // anchor groups of 64 (16)

    const size_t mask_bytes  = (size_t)W * A * sizeof(unsigned long long);
    const size_t bases_bytes = (size_t)(NSB + 1) * A * sizeof(int);

    if (ws_size < mask_bytes + bases_bytes || (A & 63)) {
        roi_pool_kernel<<<dim3(A), dim3(256), 0, stream>>>(pts, anc, out_pts, out_cnt, N, n);
        return;
    }

    unsigned long long* mask = (unsigned long long*)d_ws;
    int* bases = (int*)((char*)d_ws + mask_bytes);

    const int mask_waves = NGRP * SEGS;     // 3136
    const int emit_waves = A * NSB;         // 25600

    mask_kernel<<<dim3((mask_waves + 3) / 4), dim3(256), 0, stream>>>(
        pts, anc, mask, N, W, A, SEGS, NGRP);
    scan_kernel<<<dim3((A + 3) / 4), dim3(256), 0, stream>>>(
        mask, bases, out_pts, out_cnt, W, A, NSB, n);
    emit_kernel<<<dim3((emit_waves + 3) / 4), dim3(256), 0, stream>>>(
        pts, anc, mask, bases, out_pts, N, n, W, A, NSB);
}

// Round 5
// 152.066 us; speedup vs baseline: 1.6635x; 1.3315x over previous
//
#include <hip/hip_runtime.h>

// ROI point pooling, 4-phase coalesced version (R4 resubmit, writelane
// builtin replaced by a lane-select — the only non-standard construct left
// is readfirstlane, per cdna4_isa.md §12).
//
// prep:  bounds[A][8] = xl,xh,yl,yh,h,cx,cy,0  (8-float rows -> the mask
//        loop's per-anchor bounds become one s_load_dwordx8).
// mask:  wave = (anchor-group c of 64, word wd of 64 points). Lane = point.
//        3 vector point-loads per wave amortized over 64 anchors. Per anchor:
//        scalar-load bounds + 6 v_cmp (combined i1 mask == SGPR pair, so
//        __ballot is free) + 2 v_cndmask to park anchor j's word in lane j.
//        One coalesced store: mask[a][wd] per lane (anchor-major rows).
// scan:  wave = (a, sb of 64 words): coalesced 512B mask load, popc +
//        shfl-reduce -> sbtot[a][sb]. Also clears out_pts (0xAA-poisoned).
// emit:  wave = (a, sb): sbtot row is one cacheline -> base via shfl-reduce;
//        coalesced mask load, shfl-scan -> per-word bases; uniform ffs-loop
//        over occupied words, 64-lane-parallel point gather + ordered store.
//
// Slot of point i = #(in-box points with index < i)  == reference cumsum.

__global__ __launch_bounds__(256) void prep_kernel(
    const float* __restrict__ anc, float* __restrict__ bounds, int A)
{
    const int a = blockIdx.x * 256 + threadIdx.x;
    if (a >= A) return;
    const float cx = anc[a * 6 + 0], cy = anc[a * 6 + 1];
    const float w  = anc[a * 6 + 3], l  = anc[a * 6 + 4], h = anc[a * 6 + 5];
    float* b = bounds + (size_t)a * 8;
    b[0] = cx - 0.5f * w; b[1] = cx + 0.5f * w;
    b[2] = cy - 0.5f * l; b[3] = cy + 0.5f * l;
    b[4] = h; b[5] = cx; b[6] = cy; b[7] = 0.0f;
}

__global__ __launch_bounds__(256) void mask_kernel(
    const float* __restrict__ pts, const float* __restrict__ bounds,
    unsigned long long* __restrict__ mask,
    int N, int W, int NGRP)
{
    int wv = blockIdx.x * 4 + (threadIdx.x >> 6);
    wv = __builtin_amdgcn_readfirstlane(wv);   // provably uniform -> s_loads below
    const int lane = threadIdx.x & 63;
    if (wv >= NGRP * W) return;
    const int c  = wv / W;    // anchor group (uniform)
    const int wd = wv % W;    // 64-point word (uniform)

    const int i  = wd * 64 + lane;
    const int ic = i < N ? i : N - 1;
    const float px = pts[3 * ic + 0];
    const float py = pts[3 * ic + 1];
    const float pz = pts[3 * ic + 2];
    const bool vld = (i < N);

    unsigned int mlo = 0u, mhi = 0u;   // lane j accumulates word of anchor c*64+j
    const float* bb = bounds + (size_t)c * 64 * 8;
    #pragma unroll 8
    for (int j = 0; j < 64; ++j) {
        const float xl = bb[j * 8 + 0], xh = bb[j * 8 + 1];  // uniform -> s_load
        const float yl = bb[j * 8 + 2], yh = bb[j * 8 + 3];
        const float hh = bb[j * 8 + 4];
        const bool m = vld & (px >= xl) & (px <= xh) &
                             (py >= yl) & (py <= yh) &
                             (pz >= 0.0f) & (pz <= hh);
        const unsigned long long b = __ballot(m);   // SGPR pair
        if (lane == j) { mlo = (unsigned int)b; mhi = (unsigned int)(b >> 32); }
    }
    const unsigned long long myw = ((unsigned long long)mhi << 32) | mlo;
    mask[((size_t)(c * 64) + lane) * W + wd] = myw;  // anchor-major row
}

__global__ __launch_bounds__(256) void scan_kernel(
    const unsigned long long* __restrict__ mask, int* __restrict__ sbtot,
    float* __restrict__ out_pts, int A, int W, int NSB, int clear4)
{
    // Coalesced clear of out_pts (poisoned with 0xAA before every call).
    const int gtid = blockIdx.x * 256 + threadIdx.x;
    if (gtid < clear4) ((float4*)out_pts)[gtid] = make_float4(0.f, 0.f, 0.f, 0.f);

    const int wv   = blockIdx.x * 4 + (threadIdx.x >> 6);
    const int lane = threadIdx.x & 63;
    if (wv >= A * NSB) return;
    const int a = wv / NSB, sb = wv % NSB;
    const int wd = sb * 64 + lane;
    unsigned long long w = mask[(size_t)a * W + min(wd, W - 1)];
    if (wd >= W) w = 0ull;
    int pc = __popcll(w);
    #pragma unroll
    for (int d = 1; d < 64; d <<= 1) pc += __shfl_xor(pc, d);
    if (lane == 0) sbtot[a * 32 + sb] = pc;
}

__global__ __launch_bounds__(256) void emit_kernel(
    const float* __restrict__ pts, const float* __restrict__ bounds,
    const unsigned long long* __restrict__ mask, const int* __restrict__ sbtot,
    float* __restrict__ out_pts, float* __restrict__ out_cnt,
    int n, int A, int W, int NSB)
{
    const int wv   = blockIdx.x * 4 + (threadIdx.x >> 6);
    const int lane = threadIdx.x & 63;
    if (wv >= A * NSB) return;
    const int a = wv / NSB, sb = wv % NSB;

    const int v  = (lane < NSB) ? sbtot[a * 32 + lane] : 0;  // one cacheline
    int vb = (lane < sb) ? v : 0;
    #pragma unroll
    for (int d = 1; d < 64; d <<= 1) vb += __shfl_xor(vb, d);  // base (uniform)

    if (sb == NSB - 1) {                      // this wave also writes counts
        int vt = v;
        #pragma unroll
        for (int d = 1; d < 64; d <<= 1) vt += __shfl_xor(vt, d);
        if (lane == 0) out_cnt[a] = (float)(vt < n ? vt : n);
    }
    if (vb >= n) return;                      // uniform early-out

    const int wd = sb * 64 + lane;
    unsigned long long w = mask[(size_t)a * W + min(wd, W - 1)];
    if (wd >= W) w = 0ull;
    const int pc = __popcll(w);
    int incl = pc;
    #pragma unroll
    for (int d = 1; d < 64; d <<= 1) {
        const int t = __shfl_up(incl, d);
        if (lane >= d) incl += t;
    }
    const int wbase = vb + incl - pc;

    unsigned long long occ = __ballot(w != 0ull && wbase < n);

    const float cx = bounds[a * 8 + 5], cy = bounds[a * 8 + 6];
    float* const outa = out_pts + (size_t)a * n * 3;

    while (occ) {
        const int k = __ffsll((long long)occ) - 1;
        occ &= occ - 1ull;
        const unsigned long long b = __shfl(w, k);
        const int wb = __shfl(wbase, k);
        const bool m = (b >> lane) & 1ull;
        const int slot = wb + __popcll(b & ((1ull << lane) - 1ull));
        if (m && slot < n) {
            const int i = (sb * 64 + k) * 64 + lane;
            float* o = outa + (size_t)slot * 3;
            o[0] = pts[3 * i + 0] - cx;
            o[1] = pts[3 * i + 1] - cy;
            o[2] = pts[3 * i + 2];
        }
    }
}

// ---- Fallback (round-1 kernel) used only if ws too small / A % 64 != 0 ----
__global__ __launch_bounds__(256) void roi_pool_kernel(
    const float* __restrict__ pts, const float* __restrict__ anc,
    float* __restrict__ out_pts, float* __restrict__ out_cnt, int N, int n)
{
    const int a = blockIdx.x;
    const float cx = anc[a * 6 + 0], cy = anc[a * 6 + 1];
    const float w  = anc[a * 6 + 3], l  = anc[a * 6 + 4], h = anc[a * 6 + 5];
    const float xmin = cx - 0.5f * w, xmax = cx + 0.5f * w;
    const float ymin = cy - 0.5f * l, ymax = cy + 0.5f * l;
    const int tid = threadIdx.x, wave = tid >> 6, lane = tid & 63;
    __shared__ int s_tot[4];
    int base = 0;
    float* const outa = out_pts + (size_t)a * n * 3;
    for (int start = 0; start < N; start += 256) {
        const int i = start + tid;
        bool m = false;
        float px = 0.f, py = 0.f, pz = 0.f;
        if (i < N) {
            px = pts[3 * i]; py = pts[3 * i + 1]; pz = pts[3 * i + 2];
            m = (px >= xmin) & (px <= xmax) & (py >= ymin) & (py <= ymax) &
                (pz >= 0.0f) & (pz <= h);
        }
        const unsigned long long ball = __ballot(m);
        const int lanePfx = __popcll(ball & ((1ull << lane) - 1ull));
        if (lane == 0) s_tot[wave] = __popcll(ball);
        __syncthreads();
        const int t0 = s_tot[0], t1 = s_tot[1], t2 = s_tot[2], t3 = s_tot[3];
        int offs = base;
        if (wave > 0) offs += t0;
        if (wave > 1) offs += t1;
        if (wave > 2) offs += t2;
        const int slot = offs + lanePfx;
        if (m && slot < n) {
            float* o = outa + (size_t)slot * 3;
            o[0] = px - cx; o[1] = py - cy; o[2] = pz;
        }
        base += t0 + t1 + t2 + t3;
        __syncthreads();
        if (base >= n) break;
    }
    const int count = base < n ? base : n;
    if (tid == 0) out_cnt[a] = (float)count;
    for (int s = count + tid; s < n; s += 256) {
        float* o = outa + (size_t)s * 3;
        o[0] = 0.f; o[1] = 0.f; o[2] = 0.f;
    }
}

extern "C" void kernel_launch(void* const* d_in, const int* in_sizes, int n_in,
                              void* d_out, int out_size, void* d_ws, size_t ws_size,
                              hipStream_t stream) {
    const float* pts = (const float*)d_in[0];
    const float* anc = (const float*)d_in[1];
    const int N = in_sizes[0] / 3;          // 100000
    const int A = in_sizes[1] / 6;          // 1024
    const int n = (out_size / A - 1) / 3;   // 512

    float* out_pts = (float*)d_out;
    float* out_cnt = (float*)d_out + (size_t)A * n * 3;

    const int W    = (N + 63) / 64;         // words per anchor (1563)
    const int NSB  = (W + 63) / 64;         // 64-word super-blocks (25)
    const int NGRP = (A + 63) / 64;         // anchor groups (16)

    const size_t mask_bytes  = ((size_t)A * W + 64) * 8;   // +tail pad for guarded reads
    const size_t sbtot_bytes = (size_t)A * 32 * sizeof(int);
    const size_t bound_bytes = (size_t)A * 8 * sizeof(float);

    if (NSB > 64 || (A & 63) ||
        ws_size < mask_bytes + sbtot_bytes + bound_bytes) {
        roi_pool_kernel<<<dim3(A), dim3(256), 0, stream>>>(pts, anc, out_pts, out_cnt, N, n);
        return;
    }

    unsigned long long* mask = (unsigned long long*)d_ws;
    int*   sbtot  = (int*)((char*)d_ws + mask_bytes);
    float* bounds = (float*)((char*)d_ws + mask_bytes + sbtot_bytes);

    const int mask_waves = NGRP * W;        // 25008
    const int se_waves   = A * NSB;         // 25600
    const int clear4     = (A * n * 3) / 4; // float4s in out_pts (divisible)

    prep_kernel<<<dim3((A + 255) / 256), dim3(256), 0, stream>>>(anc, bounds, A);
    mask_kernel<<<dim3((mask_waves + 3) / 4), dim3(256), 0, stream>>>(
        pts, bounds, mask, N, W, NGRP);
    scan_kernel<<<dim3((se_waves + 3) / 4), dim3(256), 0, stream>>>(
        mask, sbtot, out_pts, A, W, NSB, clear4);
    emit_kernel<<<dim3((se_waves + 3) / 4), dim3(256), 0, stream>>>(
        pts, bounds, mask, sbtot, out_pts, out_cnt, n, A, W, NSB);
}

// Round 6
// 148.131 us; speedup vs baseline: 1.7077x; 1.0266x over previous
//
#include <hip/hip_runtime.h>

// ROI point pooling, 4-phase, all-coalesced, SALU-combined masks.
//
// prep:  bounds[A][8] = xl,xh,yl,yh,h,cx,cy,0.
// mask:  wave = (anchor-group c of 64, CH-word chunk). Lane = point.
//        Per anchor j (bounds via scalar loads, wave-uniform):
//        word = ballot(px>=xl) & ballot(px<=xh) & ... on uint64 -> the
//        v_cmp results ARE the SGPR pair masks, combines are s_and_b64.
//        Deposit anchor j's word into lane j (1 v_cmp_eq + 2 v_cndmask).
//        Store maskT[wd][a]: lane stride 8B -> 512B coalesced stores.
// scan:  wave = (c, sb of 64 words), lane = anchor: 64 coalesced loads,
//        per-lane popcount accumulate -> sbtot[sb][a] (coalesced).
// emit:  wave = (c, sb, q of 8 words), lane = anchor: per-lane base =
//        sum sbtot[k<sb] + popc of words [sb*64, sb*64+q*8); then ffs
//        bit-walk of 8 words emitting hits to ordered slots < n.
//        Distributed tail-clear ([count,n) split across chunks) and
//        counts (chunk 0) folded in -- no separate zero kernel.
//
// Slot of point i = #(in-box points with index < i)  == reference cumsum.

#define CH 2   // words per mask wave
#define NQ 8   // word-chunks per super-block in emit

__global__ __launch_bounds__(256) void prep_kernel(
    const float* __restrict__ anc, float* __restrict__ bounds, int A)
{
    const int a = blockIdx.x * 256 + threadIdx.x;
    if (a >= A) return;
    const float cx = anc[a * 6 + 0], cy = anc[a * 6 + 1];
    const float w  = anc[a * 6 + 3], l  = anc[a * 6 + 4], h = anc[a * 6 + 5];
    float* b = bounds + (size_t)a * 8;
    b[0] = cx - 0.5f * w; b[1] = cx + 0.5f * w;
    b[2] = cy - 0.5f * l; b[3] = cy + 0.5f * l;
    b[4] = h; b[5] = cx; b[6] = cy; b[7] = 0.0f;
}

__global__ __launch_bounds__(256) void mask_kernel(
    const float* __restrict__ pts, const float* __restrict__ bounds,
    unsigned long long* __restrict__ maskT, int N, int W, int A, int NCH)
{
    const int wv = __builtin_amdgcn_readfirstlane(blockIdx.x * 4 + (threadIdx.x >> 6));
    const int lane = threadIdx.x & 63;
    const int NGRP = A >> 6;
    if (wv >= NGRP * NCH) return;
    const int c   = wv / NCH;       // anchor group (uniform)
    const int wd0 = (wv % NCH) * CH;

    float px[CH], py[CH], pz[CH];
    unsigned long long zv[CH], myw[CH];
    #pragma unroll
    for (int u = 0; u < CH; ++u) {
        const int wd = wd0 + u;
        const int i  = wd * 64 + lane;
        const int ic = i < N ? i : N - 1;
        px[u] = pts[3 * ic + 0];
        py[u] = pts[3 * ic + 1];
        pz[u] = pts[3 * ic + 2];
        zv[u] = __ballot(pz[u] >= 0.0f) & __ballot(i < N);  // anchor-independent
        myw[u] = 0ull;
    }

    const float* bb = bounds + (size_t)c * 64 * 8;
    #pragma unroll 8
    for (int j = 0; j < 64; ++j) {
        const float xl = bb[j * 8 + 0], xh = bb[j * 8 + 1];  // uniform -> s_load
        const float yl = bb[j * 8 + 2], yh = bb[j * 8 + 3];
        const float hh = bb[j * 8 + 4];
        #pragma unroll
        for (int u = 0; u < CH; ++u) {
            const unsigned long long b =
                __ballot(px[u] >= xl) & __ballot(px[u] <= xh) &
                __ballot(py[u] >= yl) & __ballot(py[u] <= yh) &
                __ballot(pz[u] <= hh) & zv[u];          // s_and_b64 combines
            if (lane == j) myw[u] = b;                  // 2 v_cndmask
        }
    }
    #pragma unroll
    for (int u = 0; u < CH; ++u) {
        const int wd = wd0 + u;
        if (wd < W) maskT[(size_t)wd * A + (c * 64 + lane)] = myw[u];  // 512B coalesced
    }
}

__global__ __launch_bounds__(256) void scan_kernel(
    const unsigned long long* __restrict__ maskT, int* __restrict__ sbtot,
    int A, int W, int NSB)
{
    const int wv   = blockIdx.x * 4 + (threadIdx.x >> 6);
    const int lane = threadIdx.x & 63;
    if (wv >= (A >> 6) * NSB) return;
    const int c = wv / NSB, sb = wv % NSB;
    const int a = c * 64 + lane;
    int acc = 0;
    for (int k = 0; k < 64; ++k) {
        const int wd = sb * 64 + k;
        if (wd < W) acc += __popcll(maskT[(size_t)wd * A + a]);  // coalesced
    }
    sbtot[sb * A + a] = acc;  // coalesced
}

__global__ __launch_bounds__(256) void emit_kernel(
    const float* __restrict__ pts, const float* __restrict__ bounds,
    const unsigned long long* __restrict__ maskT, const int* __restrict__ sbtot,
    float* __restrict__ out_pts, float* __restrict__ out_cnt,
    int n, int A, int W, int NSB)
{
    const int wv   = blockIdx.x * 4 + (threadIdx.x >> 6);
    const int lane = threadIdx.x & 63;
    const int nch  = NSB * NQ;                 // chunks per anchor (200)
    if (wv >= (A >> 6) * nch) return;
    const int c   = wv / nch;
    const int cid = wv % nch;
    const int sb  = cid / NQ, q = cid % NQ;
    const int a   = c * 64 + lane;

    // Cross-sb prefix + total (coalesced sbtot row loads).
    int base = 0, total = 0;
    for (int k = 0; k < NSB; ++k) {
        const int v = sbtot[k * A + a];
        if (k < sb) base += v;
        total += v;
    }
    const int count = total < n ? total : n;
    if (cid == 0) out_cnt[a] = (float)count;

    // Distributed tail clear: chunk cid owns slots [cid*ts, cid*ts+ts).
    const int ts = (n + nch - 1) / nch;
    float* const outa = out_pts + (size_t)a * n * 3;
    for (int s = cid * ts; s < cid * ts + ts; ++s) {
        if (s >= count && s < n) {
            outa[3 * s + 0] = 0.f; outa[3 * s + 1] = 0.f; outa[3 * s + 2] = 0.f;
        }
    }

    // Intra-sb prefix up to this chunk's first word (coalesced popc loads).
    const int wds = sb * 64;
    for (int k = 0; k < q * NQ; ++k) {
        const int wd = wds + k;
        if (wd < W) base += __popcll(maskT[(size_t)wd * A + a]);
    }
    if (base >= n) return;   // all remaining slots past the clamp (per-lane)

    const float cx = bounds[a * 8 + 5], cy = bounds[a * 8 + 6];
    for (int k = 0; k < NQ; ++k) {
        const int wd = wds + q * NQ + k;
        if (wd >= W) break;
        unsigned long long w = maskT[(size_t)wd * A + a];   // coalesced
        while (w && base < n) {
            const int b = __ffsll((long long)w) - 1;
            w &= w - 1ull;
            const int i = wd * 64 + b;                      // i < N (bit never set OOB)
            float* o = outa + (size_t)base * 3;
            o[0] = pts[3 * i + 0] - cx;
            o[1] = pts[3 * i + 1] - cy;
            o[2] = pts[3 * i + 2];
            ++base;
        }
        if (base >= n) return;
    }
}

// ---- Fallback (round-1 kernel) used only if ws too small / A % 64 != 0 ----
__global__ __launch_bounds__(256) void roi_pool_kernel(
    const float* __restrict__ pts, const float* __restrict__ anc,
    float* __restrict__ out_pts, float* __restrict__ out_cnt, int N, int n)
{
    const int a = blockIdx.x;
    const float cx = anc[a * 6 + 0], cy = anc[a * 6 + 1];
    const float w  = anc[a * 6 + 3], l  = anc[a * 6 + 4], h = anc[a * 6 + 5];
    const float xmin = cx - 0.5f * w, xmax = cx + 0.5f * w;
    const float ymin = cy - 0.5f * l, ymax = cy + 0.5f * l;
    const int tid = threadIdx.x, wave = tid >> 6, lane = tid & 63;
    __shared__ int s_tot[4];
    int base = 0;
    float* const outa = out_pts + (size_t)a * n * 3;
    for (int start = 0; start < N; start += 256) {
        const int i = start + tid;
        bool m = false;
        float px = 0.f, py = 0.f, pz = 0.f;
        if (i < N) {
            px = pts[3 * i]; py = pts[3 * i + 1]; pz = pts[3 * i + 2];
            m = (px >= xmin) & (px <= xmax) & (py >= ymin) & (py <= ymax) &
                (pz >= 0.0f) & (pz <= h);
        }
        const unsigned long long ball = __ballot(m);
        const int lanePfx = __popcll(ball & ((1ull << lane) - 1ull));
        if (lane == 0) s_tot[wave] = __popcll(ball);
        __syncthreads();
        const int t0 = s_tot[0], t1 = s_tot[1], t2 = s_tot[2], t3 = s_tot[3];
        int offs = base;
        if (wave > 0) offs += t0;
        if (wave > 1) offs += t1;
        if (wave > 2) offs += t2;
        const int slot = offs + lanePfx;
        if (m && slot < n) {
            float* o = outa + (size_t)slot * 3;
            o[0] = px - cx; o[1] = py - cy; o[2] = pz;
        }
        base += t0 + t1 + t2 + t3;
        __syncthreads();
        if (base >= n) break;
    }
    const int count = base < n ? base : n;
    if (tid == 0) out_cnt[a] = (float)count;
    for (int s = count + tid; s < n; s += 256) {
        float* o = outa + (size_t)s * 3;
        o[0] = 0.f; o[1] = 0.f; o[2] = 0.f;
    }
}

extern "C" void kernel_launch(void* const* d_in, const int* in_sizes, int n_in,
                              void* d_out, int out_size, void* d_ws, size_t ws_size,
                              hipStream_t stream) {
    const float* pts = (const float*)d_in[0];
    const float* anc = (const float*)d_in[1];
    const int N = in_sizes[0] / 3;          // 100000
    const int A = in_sizes[1] / 6;          // 1024
    const int n = (out_size / A - 1) / 3;   // 512

    float* out_pts = (float*)d_out;
    float* out_cnt = (float*)d_out + (size_t)A * n * 3;

    const int W   = (N + 63) / 64;          // words per anchor (1563)
    const int NSB = (W + 63) / 64;          // 64-word super-blocks (25)
    const int NCH = (W + CH - 1) / CH;      // mask chunks per group (782)

    const size_t mask_bytes  = ((size_t)W * A + 64) * 8;
    const size_t sbtot_bytes = (size_t)NSB * A * sizeof(int);
    const size_t bound_bytes = (size_t)A * 8 * sizeof(float);

    if ((A & 63) || ws_size < mask_bytes + sbtot_bytes + bound_bytes) {
        roi_pool_kernel<<<dim3(A), dim3(256), 0, stream>>>(pts, anc, out_pts, out_cnt, N, n);
        return;
    }

    unsigned long long* maskT = (unsigned long long*)d_ws;
    int*   sbtot  = (int*)((char*)d_ws + mask_bytes);
    float* bounds = (float*)((char*)d_ws + mask_bytes + sbtot_bytes);

    const int NGRP = A >> 6;
    const int mask_waves = NGRP * NCH;       // 12512
    const int scan_waves = NGRP * NSB;       // 400
    const int emit_waves = NGRP * NSB * NQ;  // 3200

    prep_kernel<<<dim3((A + 255) / 256), dim3(256), 0, stream>>>(anc, bounds, A);
    mask_kernel<<<dim3((mask_waves + 3) / 4), dim3(256), 0, stream>>>(
        pts, bounds, maskT, N, W, A, NCH);
    scan_kernel<<<dim3((scan_waves + 3) / 4), dim3(256), 0, stream>>>(
        maskT, sbtot, A, W, NSB);
    emit_kernel<<<dim3((emit_waves + 3) / 4), dim3(256), 0, stream>>>(
        pts, bounds, maskT, sbtot, out_pts, out_cnt, n, A, W, NSB);
}